// Round 7
// baseline (281.057 us; speedup 1.0000x reference)
//
#include <hip/hip_runtime.h>
#include <hip/hip_bf16.h>
#include <math.h>

typedef __attribute__((ext_vector_type(8))) short short8;
typedef __attribute__((ext_vector_type(4))) float f32x4;

#define B_    2
#define T_    128
#define D_    256
#define H_    8
#define F_    64
#define C_    512
#define TEMB_ 512

static __device__ __forceinline__ unsigned short f2bf(float f) {
  __hip_bfloat16 h = __float2bfloat16(f);
  return reinterpret_cast<unsigned short&>(h);
}
static __device__ __forceinline__ unsigned int pk2(float a, float b) {
  return (unsigned int)f2bf(a) | ((unsigned int)f2bf(b) << 16);
}

// ---------------------------------------------------------------------------
// k_pre: merged prep + base (verified R6).
// ---------------------------------------------------------------------------
__global__ __launch_bounds__(256) void k_pre(
    const float* __restrict__ temb, const float* __restrict__ w_time,
    const float* __restrict__ b_time, const float* __restrict__ b_dist,
    const float* __restrict__ w_out, const float* __restrict__ w_dist,
    float* __restrict__ base, short* __restrict__ wsw, float* __restrict__ wdT)
{
  const int tid = threadIdx.x;
  if (blockIdx.x >= 64) {
    int gid = (blockIdx.x - 64) * 256 + tid;
    for (int s = gid; s < 32768; s += 16384) {
      int oi = s >> 10, rem = s & 1023, kjg = rem >> 6, l = rem & 63;
      int o = oi * 16 + (l & 15), c = kjg * 32 + (l >> 4) * 8;
      const float* src = w_out + (size_t)o * C_ + c;
      float4 a = *reinterpret_cast<const float4*>(src);
      float4 b = *reinterpret_cast<const float4*>(src + 4);
      uint4 v; v.x = pk2(a.x, a.y); v.y = pk2(a.z, a.w);
      v.z = pk2(b.x, b.y); v.w = pk2(b.z, b.w);
      *reinterpret_cast<uint4*>(wsw + (size_t)s * 8) = v;
    }
    if (gid < C_) {
      wdT[0 * C_ + gid] = w_dist[gid * 3 + 0];
      wdT[1 * C_ + gid] = w_dist[gid * 3 + 1];
      wdT[2 * C_ + gid] = w_dist[gid * 3 + 2];
    }
    return;
  }
  __shared__ float tt[32][64];
  __shared__ float wt[64][65];
  const int bt0 = (blockIdx.x & 7) * 32;
  const int c0  = (blockIdx.x >> 3) * 64;
  const int cl  = tid & 63;
  const int g   = tid >> 6;
  float acc[8] = {0.f,0.f,0.f,0.f,0.f,0.f,0.f,0.f};

  for (int k0 = 0; k0 < TEMB_; k0 += 64) {
#pragma unroll
    for (int i = 0; i < 8; ++i) {
      int idx = tid + i * 256; int r = idx >> 6, k = idx & 63;
      tt[r][k] = temb[(size_t)(bt0 + r) * TEMB_ + k0 + k];
    }
#pragma unroll
    for (int i = 0; i < 16; ++i) {
      int idx = tid + i * 256; int r = idx >> 6, k = idx & 63;
      wt[r][k] = w_time[(size_t)(c0 + r) * TEMB_ + k0 + k];
    }
    __syncthreads();
#pragma unroll
    for (int k = 0; k < 64; ++k) {
      float w = wt[cl][k];
#pragma unroll
      for (int j = 0; j < 8; ++j) acc[j] += tt[g + 4 * j][k] * w;
    }
    __syncthreads();
  }
  float bb = b_time[c0 + cl] + b_dist[c0 + cl];
#pragma unroll
  for (int j = 0; j < 8; ++j)
    base[(size_t)(bt0 + g + 4 * j) * C_ + c0 + cl] = acc[j] + bb;
}

// ---------------------------------------------------------------------------
// k_rpe: block = (bt, o-half), 512 threads.  R[s][o] -> Rg bf16 (verified R6).
// ---------------------------------------------------------------------------
__global__ __launch_bounds__(512, 4) void k_rpe(
    const float* __restrict__ pd, const float* __restrict__ base,
    const float* __restrict__ wdT, const short* __restrict__ wsw,
    const float* __restrict__ b_out, unsigned short* __restrict__ Rg)
{
  __shared__ __align__(16) short At[8192];
  __shared__ float df[3][T_];

  const int bx   = blockIdx.x;
  const int bt   = bx >> 1;
  const int half = bx & 1;
  const int b    = bt >> 7;
  const int t    = bt & 127;
  const int tid  = threadIdx.x;
  const int lane = tid & 63;
  const int wave = tid >> 6;
  const int lanem = lane & 15;
  const int laneg = lane >> 4;

  if (tid < T_) {
    float p = pd[((size_t)b * T_ + t) * T_ + tid];
    df[0][tid] = log1pf(fmaxf(p, 0.f));
    df[1][tid] = log1pf(fmaxf(-p, 0.f));
    df[2][tid] = (p == 0.f) ? 1.f : 0.f;
  }

  const int wm = wave >> 2;
  const int wn = wave & 3;
  const int s_low = tid & 15;
  const int cg    = (tid >> 4) & 7;
  const int si_b  = (tid >> 7) * 2;
  const int kjA   = cg >> 2;
  const int cgl   = cg & 3;
  const int laneslotA = s_low + 16 * cgl;
  const float* baserow = base + (size_t)bt * C_;

  f32x4 acc[4][4];
#pragma unroll
  for (int mi = 0; mi < 4; ++mi)
#pragma unroll
    for (int ni = 0; ni < 4; ++ni) acc[mi][ni] = (f32x4){0.f, 0.f, 0.f, 0.f};

  for (int kt = 0; kt < 8; ++kt) {
    __syncthreads();
    short8 b0[4], b1[4];
#pragma unroll
    for (int ni = 0; ni < 4; ++ni) {
      int oi = half * 16 + wn * 4 + ni;
      b0[ni] = *reinterpret_cast<const short8*>(
          wsw + ((size_t)(oi * 16 + kt * 2 + 0) * 64 + lane) * 8);
    }
    {
      const int cglob = kt * 64 + cg * 8;
      float4 bs0 = *reinterpret_cast<const float4*>(baserow + cglob);
      float4 bs1 = *reinterpret_cast<const float4*>(baserow + cglob + 4);
      float4 wa0 = *reinterpret_cast<const float4*>(wdT + cglob);
      float4 wa1 = *reinterpret_cast<const float4*>(wdT + cglob + 4);
      float4 wb0 = *reinterpret_cast<const float4*>(wdT + C_ + cglob);
      float4 wb1 = *reinterpret_cast<const float4*>(wdT + C_ + cglob + 4);
      float4 wc0 = *reinterpret_cast<const float4*>(wdT + 2 * C_ + cglob);
      float4 wc1 = *reinterpret_cast<const float4*>(wdT + 2 * C_ + cglob + 4);
#pragma unroll
      for (int q = 0; q < 2; ++q) {
        int si = si_b + q;
        int s  = si * 16 + s_low;
        float d0 = df[0][s], d1 = df[1][s], d2 = df[2][s];
        uint4 v;
        {
          float x0 = bs0.x + d0 * wa0.x + d1 * wb0.x + d2 * wc0.x;
          float x1 = bs0.y + d0 * wa0.y + d1 * wb0.y + d2 * wc0.y;
          float x2 = bs0.z + d0 * wa0.z + d1 * wb0.z + d2 * wc0.z;
          float x3 = bs0.w + d0 * wa0.w + d1 * wb0.w + d2 * wc0.w;
          x0 = x0 / (1.f + __expf(-x0)); x1 = x1 / (1.f + __expf(-x1));
          x2 = x2 / (1.f + __expf(-x2)); x3 = x3 / (1.f + __expf(-x3));
          v.x = pk2(x0, x1); v.y = pk2(x2, x3);
        }
        {
          float x0 = bs1.x + d0 * wa1.x + d1 * wb1.x + d2 * wc1.x;
          float x1 = bs1.y + d0 * wa1.y + d1 * wb1.y + d2 * wc1.y;
          float x2 = bs1.z + d0 * wa1.z + d1 * wb1.z + d2 * wc1.z;
          float x3 = bs1.w + d0 * wa1.w + d1 * wb1.w + d2 * wc1.w;
          x0 = x0 / (1.f + __expf(-x0)); x1 = x1 / (1.f + __expf(-x1));
          x2 = x2 / (1.f + __expf(-x2)); x3 = x3 / (1.f + __expf(-x3));
          v.z = pk2(x0, x1); v.w = pk2(x2, x3);
        }
        *reinterpret_cast<uint4*>(&At[((si * 2 + kjA) * 64 + laneslotA) * 8]) = v;
      }
    }
#pragma unroll
    for (int ni = 0; ni < 4; ++ni) {
      int oi = half * 16 + wn * 4 + ni;
      b1[ni] = *reinterpret_cast<const short8*>(
          wsw + ((size_t)(oi * 16 + kt * 2 + 1) * 64 + lane) * 8);
    }
    __syncthreads();
    {
      short8 a[4];
#pragma unroll
      for (int mi = 0; mi < 4; ++mi)
        a[mi] = *reinterpret_cast<const short8*>(
            &At[(((wm * 4 + mi) * 2 + 0) * 64 + lane) * 8]);
#pragma unroll
      for (int ni = 0; ni < 4; ++ni)
#pragma unroll
        for (int mi = 0; mi < 4; ++mi)
          acc[mi][ni] = __builtin_amdgcn_mfma_f32_16x16x32_bf16(
              b0[ni], a[mi], acc[mi][ni], 0, 0, 0);
#pragma unroll
      for (int mi = 0; mi < 4; ++mi)
        a[mi] = *reinterpret_cast<const short8*>(
            &At[(((wm * 4 + mi) * 2 + 1) * 64 + lane) * 8]);
#pragma unroll
      for (int ni = 0; ni < 4; ++ni)
#pragma unroll
        for (int mi = 0; mi < 4; ++mi)
          acc[mi][ni] = __builtin_amdgcn_mfma_f32_16x16x32_bf16(
              b1[ni], a[mi], acc[mi][ni], 0, 0, 0);
    }
  }

  unsigned short* Rbt = Rg + (size_t)bt * T_ * C_;
#pragma unroll
  for (int ni = 0; ni < 4; ++ni) {
    const int o0 = half * 256 + wn * 64 + ni * 16 + laneg * 4;
    const float4 bo4 = *reinterpret_cast<const float4*>(b_out + o0);
#pragma unroll
    for (int mi = 0; mi < 4; ++mi) {
      const int s = wm * 64 + mi * 16 + lanem;
      uint2 v;
      v.x = pk2(acc[mi][ni][0] + bo4.x, acc[mi][ni][1] + bo4.y);
      v.y = pk2(acc[mi][ni][2] + bo4.z, acc[mi][ni][3] + bo4.w);
      *reinterpret_cast<uint2*>(Rbt + (size_t)s * C_ + o0) = v;
    }
  }
}

// ---------------------------------------------------------------------------
// k_qkr (RESTRUCTURED for DRAM streaming): bx = dg*64 + g, g=(b,h,tq).
// All 16 dg-blocks of a (b,h,tq) share one XCD (bx%8 const) -> R slice
// L2-resident.  Per block: 16 d x 32 t; wave owns 8 t.  Per t: A = R frags
// (s-rows), B = qk frag (d-rows); D gives lane 4 consecutive s -> direct
// float4 stores.  qk reads and out writes advance sequentially along t in
// 16 per-d streams.  No LDS, no barriers.
// ---------------------------------------------------------------------------
__global__ __launch_bounds__(256, 4) void k_qkr(
    const float* __restrict__ qk, const unsigned short* __restrict__ Rg,
    float* __restrict__ out)
{
  const int bx = blockIdx.x;
  const int g  = bx & 63;
  const int dg = bx >> 6;
  const int b  = g >> 5;
  const int h  = (g >> 2) & 7;
  const int tq = g & 3;
  const int tid  = threadIdx.x;
  const int lane = tid & 63;
  const int wave = tid >> 6;
  const int lanem = lane & 15;
  const int laneg = lane >> 4;

  const size_t HTF = (size_t)H_ * T_ * F_;   // 65536
  const size_t HTT = (size_t)H_ * T_ * T_;   // 131072
  const int d = dg * 16 + lanem;

  const float* qkrow = qk + (size_t)b * D_ * HTF + (size_t)d * HTF
                          + (size_t)h * T_ * F_ + laneg * 8;
  float* outrow = out + (size_t)(b * D_ + d) * HTT + (size_t)h * T_ * T_;
  const unsigned short* Rbase = Rg + (size_t)b * T_ * T_ * C_
                                   + (size_t)lanem * C_ + h * F_ + laneg * 8;

  const int t0 = tq * 32 + wave * 8;
#pragma unroll
  for (int ti = 0; ti < 8; ++ti) {
    const int t = t0 + ti;
    // qk B-frag loads (sequential at t*F within each d-row)
    const float* qs = qkrow + (size_t)t * F_;
    float4 q0 = *reinterpret_cast<const float4*>(qs);
    float4 q1 = *reinterpret_cast<const float4*>(qs + 4);
    float4 q2 = *reinterpret_cast<const float4*>(qs + 32);
    float4 q3 = *reinterpret_cast<const float4*>(qs + 36);
    // R A-frag loads for this t (L2-hot slice)
    const unsigned short* rs = Rbase + (size_t)t * T_ * C_;
    short8 av[2][8];
#pragma unroll
    for (int kj = 0; kj < 2; ++kj)
#pragma unroll
      for (int ni = 0; ni < 8; ++ni)
        av[kj][ni] = *reinterpret_cast<const short8*>(
            rs + (size_t)ni * 16 * C_ + kj * 32);
    // convert qk to bf16 frags
    short8 qb0, qb1;
    {
      union { uint4 u; short8 s; } cv;
      cv.u.x = pk2(q0.x, q0.y); cv.u.y = pk2(q0.z, q0.w);
      cv.u.z = pk2(q1.x, q1.y); cv.u.w = pk2(q1.z, q1.w);
      qb0 = cv.s;
      cv.u.x = pk2(q2.x, q2.y); cv.u.y = pk2(q2.z, q2.w);
      cv.u.z = pk2(q3.x, q3.y); cv.u.w = pk2(q3.z, q3.w);
      qb1 = cv.s;
    }
    // MFMA: D[col = d (lanem)][row = s (laneg*4+reg)]
    f32x4 ac[8];
#pragma unroll
    for (int ni = 0; ni < 8; ++ni) ac[ni] = (f32x4){0.f, 0.f, 0.f, 0.f};
#pragma unroll
    for (int ni = 0; ni < 8; ++ni)
      ac[ni] = __builtin_amdgcn_mfma_f32_16x16x32_bf16(av[0][ni], qb0, ac[ni], 0, 0, 0);
#pragma unroll
    for (int ni = 0; ni < 8; ++ni)
      ac[ni] = __builtin_amdgcn_mfma_f32_16x16x32_bf16(av[1][ni], qb1, ac[ni], 0, 0, 0);
    // stores: 4 consecutive s per lane; sequential at t*T within each d-row
    float* os = outrow + (size_t)t * T_ + laneg * 4;
#pragma unroll
    for (int ni = 0; ni < 8; ++ni)
      *reinterpret_cast<float4*>(os + ni * 16) =
          (float4){ac[ni][0], ac[ni][1], ac[ni][2], ac[ni][3]};
  }
}

extern "C" void kernel_launch(void* const* d_in, const int* in_sizes, int n_in,
                              void* d_out, int out_size, void* d_ws, size_t ws_size,
                              hipStream_t stream) {
  const float* qk     = (const float*)d_in[0];
  const float* pd     = (const float*)d_in[1];
  const float* temb   = (const float*)d_in[2];
  const float* w_dist = (const float*)d_in[3];
  const float* b_dist = (const float*)d_in[4];
  const float* w_time = (const float*)d_in[5];
  const float* b_time = (const float*)d_in[6];
  const float* w_out  = (const float*)d_in[7];
  const float* b_out  = (const float*)d_in[8];
  float* out = (float*)d_out;

  char* ws = (char*)d_ws;
  float* base          = (float*)(ws);                    // 524288 B
  float* wdT           = (float*)(ws + 524288);           //   8192 B slot
  short* wsw           = (short*)(ws + 532480);           // 524288 B
  unsigned short* Rg   = (unsigned short*)(ws + 1056768); // 33554432 B

  hipLaunchKernelGGL(k_pre, dim3(128), dim3(256), 0, stream,
                     temb, w_time, b_time, b_dist, w_out, w_dist,
                     base, wsw, wdT);
  hipLaunchKernelGGL(k_rpe, dim3(2 * B_ * T_), dim3(512), 0, stream,
                     pd, base, wdT, wsw, b_out, Rg);
  hipLaunchKernelGGL(k_qkr, dim3(1024), dim3(256), 0, stream,
                     qk, Rg, out);
}

// Round 8
// 195.358 us; speedup vs baseline: 1.4387x; 1.4387x over previous
//
#include <hip/hip_runtime.h>
#include <hip/hip_bf16.h>
#include <math.h>

typedef __attribute__((ext_vector_type(8))) short short8;
typedef __attribute__((ext_vector_type(4))) float f32x4;

#define B_    2
#define T_    128
#define D_    256
#define H_    8
#define F_    64
#define C_    512
#define TEMB_ 512
#define HTF_  65536
#define HTT_  131072

static __device__ __forceinline__ unsigned short f2bf(float f) {
  __hip_bfloat16 h = __float2bfloat16(f);
  return reinterpret_cast<unsigned short&>(h);
}
static __device__ __forceinline__ unsigned int pk2(float a, float b) {
  return (unsigned int)f2bf(a) | ((unsigned int)f2bf(b) << 16);
}

// async 16B global->LDS DMA (no VGPR destination -> free MLP)
static __device__ __forceinline__ void dma16(const float* g, float* l) {
  __builtin_amdgcn_global_load_lds(
      (const __attribute__((address_space(1))) unsigned int*)g,
      (__attribute__((address_space(3))) unsigned int*)l, 16, 0, 0);
}

// ---------------------------------------------------------------------------
// k_pre: merged prep + base (verified R6/R7).
// ---------------------------------------------------------------------------
__global__ __launch_bounds__(256) void k_pre(
    const float* __restrict__ temb, const float* __restrict__ w_time,
    const float* __restrict__ b_time, const float* __restrict__ b_dist,
    const float* __restrict__ w_out, const float* __restrict__ w_dist,
    float* __restrict__ base, short* __restrict__ wsw, float* __restrict__ wdT)
{
  const int tid = threadIdx.x;
  if (blockIdx.x >= 64) {
    int gid = (blockIdx.x - 64) * 256 + tid;
    for (int s = gid; s < 32768; s += 16384) {
      int oi = s >> 10, rem = s & 1023, kjg = rem >> 6, l = rem & 63;
      int o = oi * 16 + (l & 15), c = kjg * 32 + (l >> 4) * 8;
      const float* src = w_out + (size_t)o * C_ + c;
      float4 a = *reinterpret_cast<const float4*>(src);
      float4 b = *reinterpret_cast<const float4*>(src + 4);
      uint4 v; v.x = pk2(a.x, a.y); v.y = pk2(a.z, a.w);
      v.z = pk2(b.x, b.y); v.w = pk2(b.z, b.w);
      *reinterpret_cast<uint4*>(wsw + (size_t)s * 8) = v;
    }
    if (gid < C_) {
      wdT[0 * C_ + gid] = w_dist[gid * 3 + 0];
      wdT[1 * C_ + gid] = w_dist[gid * 3 + 1];
      wdT[2 * C_ + gid] = w_dist[gid * 3 + 2];
    }
    return;
  }
  __shared__ float tt[32][64];
  __shared__ float wt[64][65];
  const int bt0 = (blockIdx.x & 7) * 32;
  const int c0  = (blockIdx.x >> 3) * 64;
  const int cl  = tid & 63;
  const int g   = tid >> 6;
  float acc[8] = {0.f,0.f,0.f,0.f,0.f,0.f,0.f,0.f};

  for (int k0 = 0; k0 < TEMB_; k0 += 64) {
#pragma unroll
    for (int i = 0; i < 8; ++i) {
      int idx = tid + i * 256; int r = idx >> 6, k = idx & 63;
      tt[r][k] = temb[(size_t)(bt0 + r) * TEMB_ + k0 + k];
    }
#pragma unroll
    for (int i = 0; i < 16; ++i) {
      int idx = tid + i * 256; int r = idx >> 6, k = idx & 63;
      wt[r][k] = w_time[(size_t)(c0 + r) * TEMB_ + k0 + k];
    }
    __syncthreads();
#pragma unroll
    for (int k = 0; k < 64; ++k) {
      float w = wt[cl][k];
#pragma unroll
      for (int j = 0; j < 8; ++j) acc[j] += tt[g + 4 * j][k] * w;
    }
    __syncthreads();
  }
  float bb = b_time[c0 + cl] + b_dist[c0 + cl];
#pragma unroll
  for (int j = 0; j < 8; ++j)
    base[(size_t)(bt0 + g + 4 * j) * C_ + c0 + cl] = acc[j] + bb;
}

// ---------------------------------------------------------------------------
// k_rpe: block = (bt, o-half), 512 threads.  R[s][o] -> Rg bf16 (verified R6).
// ---------------------------------------------------------------------------
__global__ __launch_bounds__(512, 4) void k_rpe(
    const float* __restrict__ pd, const float* __restrict__ base,
    const float* __restrict__ wdT, const short* __restrict__ wsw,
    const float* __restrict__ b_out, unsigned short* __restrict__ Rg)
{
  __shared__ __align__(16) short At[8192];
  __shared__ float df[3][T_];

  const int bx   = blockIdx.x;
  const int bt   = bx >> 1;
  const int half = bx & 1;
  const int b    = bt >> 7;
  const int t    = bt & 127;
  const int tid  = threadIdx.x;
  const int lane = tid & 63;
  const int wave = tid >> 6;
  const int lanem = lane & 15;
  const int laneg = lane >> 4;

  if (tid < T_) {
    float p = pd[((size_t)b * T_ + t) * T_ + tid];
    df[0][tid] = log1pf(fmaxf(p, 0.f));
    df[1][tid] = log1pf(fmaxf(-p, 0.f));
    df[2][tid] = (p == 0.f) ? 1.f : 0.f;
  }

  const int wm = wave >> 2;
  const int wn = wave & 3;
  const int s_low = tid & 15;
  const int cg    = (tid >> 4) & 7;
  const int si_b  = (tid >> 7) * 2;
  const int kjA   = cg >> 2;
  const int cgl   = cg & 3;
  const int laneslotA = s_low + 16 * cgl;
  const float* baserow = base + (size_t)bt * C_;

  f32x4 acc[4][4];
#pragma unroll
  for (int mi = 0; mi < 4; ++mi)
#pragma unroll
    for (int ni = 0; ni < 4; ++ni) acc[mi][ni] = (f32x4){0.f, 0.f, 0.f, 0.f};

  for (int kt = 0; kt < 8; ++kt) {
    __syncthreads();
    short8 b0[4], b1[4];
#pragma unroll
    for (int ni = 0; ni < 4; ++ni) {
      int oi = half * 16 + wn * 4 + ni;
      b0[ni] = *reinterpret_cast<const short8*>(
          wsw + ((size_t)(oi * 16 + kt * 2 + 0) * 64 + lane) * 8);
    }
    {
      const int cglob = kt * 64 + cg * 8;
      float4 bs0 = *reinterpret_cast<const float4*>(baserow + cglob);
      float4 bs1 = *reinterpret_cast<const float4*>(baserow + cglob + 4);
      float4 wa0 = *reinterpret_cast<const float4*>(wdT + cglob);
      float4 wa1 = *reinterpret_cast<const float4*>(wdT + cglob + 4);
      float4 wb0 = *reinterpret_cast<const float4*>(wdT + C_ + cglob);
      float4 wb1 = *reinterpret_cast<const float4*>(wdT + C_ + cglob + 4);
      float4 wc0 = *reinterpret_cast<const float4*>(wdT + 2 * C_ + cglob);
      float4 wc1 = *reinterpret_cast<const float4*>(wdT + 2 * C_ + cglob + 4);
#pragma unroll
      for (int q = 0; q < 2; ++q) {
        int si = si_b + q;
        int s  = si * 16 + s_low;
        float d0 = df[0][s], d1 = df[1][s], d2 = df[2][s];
        uint4 v;
        {
          float x0 = bs0.x + d0 * wa0.x + d1 * wb0.x + d2 * wc0.x;
          float x1 = bs0.y + d0 * wa0.y + d1 * wb0.y + d2 * wc0.y;
          float x2 = bs0.z + d0 * wa0.z + d1 * wb0.z + d2 * wc0.z;
          float x3 = bs0.w + d0 * wa0.w + d1 * wb0.w + d2 * wc0.w;
          x0 = x0 / (1.f + __expf(-x0)); x1 = x1 / (1.f + __expf(-x1));
          x2 = x2 / (1.f + __expf(-x2)); x3 = x3 / (1.f + __expf(-x3));
          v.x = pk2(x0, x1); v.y = pk2(x2, x3);
        }
        {
          float x0 = bs1.x + d0 * wa1.x + d1 * wb1.x + d2 * wc1.x;
          float x1 = bs1.y + d0 * wa1.y + d1 * wb1.y + d2 * wc1.y;
          float x2 = bs1.z + d0 * wa1.z + d1 * wb1.z + d2 * wc1.z;
          float x3 = bs1.w + d0 * wa1.w + d1 * wb1.w + d2 * wc1.w;
          x0 = x0 / (1.f + __expf(-x0)); x1 = x1 / (1.f + __expf(-x1));
          x2 = x2 / (1.f + __expf(-x2)); x3 = x3 / (1.f + __expf(-x3));
          v.z = pk2(x0, x1); v.w = pk2(x2, x3);
        }
        *reinterpret_cast<uint4*>(&At[((si * 2 + kjA) * 64 + laneslotA) * 8]) = v;
      }
    }
#pragma unroll
    for (int ni = 0; ni < 4; ++ni) {
      int oi = half * 16 + wn * 4 + ni;
      b1[ni] = *reinterpret_cast<const short8*>(
          wsw + ((size_t)(oi * 16 + kt * 2 + 1) * 64 + lane) * 8);
    }
    __syncthreads();
    {
      short8 a[4];
#pragma unroll
      for (int mi = 0; mi < 4; ++mi)
        a[mi] = *reinterpret_cast<const short8*>(
            &At[(((wm * 4 + mi) * 2 + 0) * 64 + lane) * 8]);
#pragma unroll
      for (int ni = 0; ni < 4; ++ni)
#pragma unroll
        for (int mi = 0; mi < 4; ++mi)
          acc[mi][ni] = __builtin_amdgcn_mfma_f32_16x16x32_bf16(
              b0[ni], a[mi], acc[mi][ni], 0, 0, 0);
#pragma unroll
      for (int mi = 0; mi < 4; ++mi)
        a[mi] = *reinterpret_cast<const short8*>(
            &At[(((wm * 4 + mi) * 2 + 1) * 64 + lane) * 8]);
#pragma unroll
      for (int ni = 0; ni < 4; ++ni)
#pragma unroll
        for (int mi = 0; mi < 4; ++mi)
          acc[mi][ni] = __builtin_amdgcn_mfma_f32_16x16x32_bf16(
              b1[ni], a[mi], acc[mi][ni], 0, 0, 0);
    }
  }

  unsigned short* Rbt = Rg + (size_t)bt * T_ * C_;
#pragma unroll
  for (int ni = 0; ni < 4; ++ni) {
    const int o0 = half * 256 + wn * 64 + ni * 16 + laneg * 4;
    const float4 bo4 = *reinterpret_cast<const float4*>(b_out + o0);
#pragma unroll
    for (int mi = 0; mi < 4; ++mi) {
      const int s = wm * 64 + mi * 16 + lanem;
      uint2 v;
      v.x = pk2(acc[mi][ni][0] + bo4.x, acc[mi][ni][1] + bo4.y);
      v.y = pk2(acc[mi][ni][2] + bo4.z, acc[mi][ni][3] + bo4.w);
      *reinterpret_cast<uint2*>(Rbt + (size_t)s * C_ + o0) = v;
    }
  }
}

// ---------------------------------------------------------------------------
// k_qkr: block = (bt,h) [2048 blocks], 256 thr, NO barriers.
// wave = d-quarter (64 d = 4 chunks of 16).  qk staged per-wave via
// global_load_lds (async DMA, 16B), double-buffered, counted vmcnt ->
// deep read MLP without VGPR cost.  LDS tile bank-swizzled via pre-swizzled
// GLOBAL source (key (d&7)<<1, 16B-granule, pair-contiguous).
// brf (R s-row frags) resident in 32 VGPR from global (L2-hot).
// MFMA: D col = d (lanem), rows = s -> float4 stores of 4 consecutive s.
// ---------------------------------------------------------------------------
__global__ __launch_bounds__(256, 4) void k_qkr(
    const float* __restrict__ qk, const unsigned short* __restrict__ Rg,
    float* __restrict__ out)
{
  __shared__ __align__(16) float st[4][2][1024];   // 32 KB: per-wave dbuf

  const int bx = blockIdx.x;
  const int h  = bx & 7;
  const int bt = bx >> 3;
  const int b  = bt >> 7;
  const int t  = bt & 127;
  const int tid  = threadIdx.x;
  const int lane = tid & 63;
  const int wave = tid >> 6;
  const int lanem = lane & 15;
  const int laneg = lane >> 4;

  const float* qkb = qk + (size_t)b * D_ * HTF_ + (size_t)h * T_ * F_ + (size_t)t * F_;
  float* outb = out + (size_t)b * D_ * HTT_ + (size_t)h * T_ * T_ + (size_t)t * T_;
  const unsigned short* Rb = Rg + (size_t)bt * T_ * C_ + h * F_;

  // ---- R frags (A-operand), resident (16 loads, L2-hot) ----
  short8 brf[2][8];
#pragma unroll
  for (int kj = 0; kj < 2; ++kj)
#pragma unroll
    for (int ni = 0; ni < 8; ++ni)
      brf[kj][ni] = *reinterpret_cast<const short8*>(
          Rb + (size_t)(ni * 16 + lanem) * C_ + kj * 32 + laneg * 8);

  // ---- async stage: chunk c = 16 d-rows x 64 f fp32 = 4 KB, 4 DMA insts ----
  float* buf0 = &st[wave][0][0];
  float* buf1 = &st[wave][1][0];
  auto STAGE = [&](float* buf, int c) {
#pragma unroll
    for (int j = 0; j < 4; ++j) {
      const int dl = j * 4 + laneg;                 // d within chunk for this slot
      const int g  = lanem ^ ((dl & 7) << 1);       // swizzled granule
      const float* src = qkb + (size_t)(c * 16 + dl) * HTF_ + g * 4;
      dma16(src, buf + j * 256);                    // wave-uniform LDS base
    }
  };

  const int c0 = wave * 4;
  STAGE(buf0, c0 + 0);
  STAGE(buf1, c0 + 1);
  __builtin_amdgcn_sched_barrier(0);

#pragma unroll
  for (int i = 0; i < 4; ++i) {
    const int c = c0 + i;
    float* cur = (i & 1) ? buf1 : buf0;
    // FIFO-counted waits (brf16, S0, S1, [S2, st0(8)], [S3, st1(8)], [st2], [st3])
    if (i == 0)      asm volatile("s_waitcnt vmcnt(4)"  ::: "memory");
    else if (i == 1) asm volatile("s_waitcnt vmcnt(12)" ::: "memory");
    else if (i == 2) asm volatile("s_waitcnt vmcnt(20)" ::: "memory");
    else             asm volatile("s_waitcnt vmcnt(16)" ::: "memory");
    __builtin_amdgcn_sched_barrier(0);

    // ds_read qk rows (swizzled): qb0 = f[laneg*8..+8), qb1 = +32
    const int key = (lanem & 7) << 1;
    const int bd  = lanem * 64;
    const int g0  = (2 * laneg) ^ key;
    const int g1  = (8 + 2 * laneg) ^ key;
    float4 f0 = *reinterpret_cast<const float4*>(cur + bd + g0 * 4);
    float4 f1 = *reinterpret_cast<const float4*>(cur + bd + g0 * 4 + 4);
    float4 f2 = *reinterpret_cast<const float4*>(cur + bd + g1 * 4);
    float4 f3 = *reinterpret_cast<const float4*>(cur + bd + g1 * 4 + 4);
    asm volatile("s_waitcnt lgkmcnt(0)" ::: "memory");
    __builtin_amdgcn_sched_barrier(0);
    if (i < 2) STAGE(cur, c + 2);   // reuse buffer for chunk i+2

    short8 qb0, qb1;
    {
      union { uint4 u; short8 s; } cv;
      cv.u.x = pk2(f0.x, f0.y); cv.u.y = pk2(f0.z, f0.w);
      cv.u.z = pk2(f1.x, f1.y); cv.u.w = pk2(f1.z, f1.w);
      qb0 = cv.s;
      cv.u.x = pk2(f2.x, f2.y); cv.u.y = pk2(f2.z, f2.w);
      cv.u.z = pk2(f3.x, f3.y); cv.u.w = pk2(f3.z, f3.w);
      qb1 = cv.s;
    }
    f32x4 ac[8];
#pragma unroll
    for (int ni = 0; ni < 8; ++ni) ac[ni] = (f32x4){0.f, 0.f, 0.f, 0.f};
#pragma unroll
    for (int ni = 0; ni < 8; ++ni)
      ac[ni] = __builtin_amdgcn_mfma_f32_16x16x32_bf16(brf[0][ni], qb0, ac[ni], 0, 0, 0);
#pragma unroll
    for (int ni = 0; ni < 8; ++ni)
      ac[ni] = __builtin_amdgcn_mfma_f32_16x16x32_bf16(brf[1][ni], qb1, ac[ni], 0, 0, 0);

    // stores: lane d = c*16+lanem; float4 of s = ni*16 + laneg*4 .. +4
    float* od = outb + (size_t)(c * 16 + lanem) * HTT_ + laneg * 4;
#pragma unroll
    for (int ni = 0; ni < 8; ++ni)
      *reinterpret_cast<float4*>(od + ni * 16) =
          (float4){ac[ni][0], ac[ni][1], ac[ni][2], ac[ni][3]};
  }
}

extern "C" void kernel_launch(void* const* d_in, const int* in_sizes, int n_in,
                              void* d_out, int out_size, void* d_ws, size_t ws_size,
                              hipStream_t stream) {
  const float* qk     = (const float*)d_in[0];
  const float* pd     = (const float*)d_in[1];
  const float* temb   = (const float*)d_in[2];
  const float* w_dist = (const float*)d_in[3];
  const float* b_dist = (const float*)d_in[4];
  const float* w_time = (const float*)d_in[5];
  const float* b_time = (const float*)d_in[6];
  const float* w_out  = (const float*)d_in[7];
  const float* b_out  = (const float*)d_in[8];
  float* out = (float*)d_out;

  char* ws = (char*)d_ws;
  float* base          = (float*)(ws);                    // 524288 B
  float* wdT           = (float*)(ws + 524288);           //   8192 B slot
  short* wsw           = (short*)(ws + 532480);           // 524288 B
  unsigned short* Rg   = (unsigned short*)(ws + 1056768); // 33554432 B

  hipLaunchKernelGGL(k_pre, dim3(128), dim3(256), 0, stream,
                     temb, w_time, b_time, b_dist, w_out, w_dist,
                     base, wsw, wdT);
  hipLaunchKernelGGL(k_rpe, dim3(2 * B_ * T_), dim3(512), 0, stream,
                     pd, base, wdT, wsw, b_out, Rg);
  hipLaunchKernelGGL(k_qkr, dim3(B_ * T_ * H_), dim3(256), 0, stream,
                     qk, Rg, out);
}